// Round 3
// baseline (2016.269 us; speedup 1.0000x reference)
//
#include <hip/hip_runtime.h>

#define TT 512
#define BB 256
#define CC 65
#define HALFC 32
#define HID 128
#define ODIM 10

__device__ __forceinline__ float ftanh(float x) {
  float e = __expf(-2.f * fabsf(x));
  float r = (1.f - e) / (1.f + e);
  return copysignf(r, x);
}
__device__ __forceinline__ float fsig(float x) {
  float e = __expf(-fabsf(x));
  float p = 1.f / (1.f + e);
  return (x >= 0.f) ? p : (1.f - p);
}
// VALU-pipe cross-lane add within each row of 16 lanes (rotate-reduce).
// dpp ctrl must be a compile-time constant -> template parameter.
template <int CTRL>
__device__ __forceinline__ float dpp_add(float x) {
  return x + __int_as_float(__builtin_amdgcn_update_dpp(
      0, __float_as_int(x), CTRL, 0xF, 0xF, true));
}
__device__ __forceinline__ float red16(float x) {
  x = dpp_add<0x121>(x);  // row_ror:1
  x = dpp_add<0x122>(x);  // row_ror:2
  x = dpp_add<0x124>(x);  // row_ror:4
  x = dpp_add<0x128>(x);  // row_ror:8
  return x;               // every lane in the 16-row holds the full sum
}
// float4-granularity LDS swizzle: spreads the 16 kk-read addresses over all
// 8 bank groups (2-way alias = free). Involution: swz(swz(f)) == f.
__device__ __forceinline__ int swz(int f) { return f ^ ((f >> 3) & 3); }

// Per-t scalars: idx (int bits), fr, td, tsub
__global__ void prep0(const float* __restrict__ times, float4* __restrict__ si,
                      int* __restrict__ anyobs) {
  __shared__ float ts[TT];
  int t = threadIdx.x;
  ts[t] = times[t];
  __syncthreads();
  float tv = ts[t];
  int cnt = 0;
  for (int jj = 0; jj < TT; ++jj) cnt += (tv > ts[jj]) ? 1 : 0;
  int idx = cnt - 1;
  idx = min(max(idx, 0), TT - 2);
  float4 o;
  o.x = __int_as_float(idx);
  o.y = tv - ts[idx];
  o.z = (t == 0) ? 0.f : (tv - ts[t - 1]);
  o.w = (t == 0) ? ts[0] : ts[t - 1];
  si[t] = o;
  anyobs[t] = 0;
}

// obs[b,t] = max over diffed channels 1..32 > 0.5 ; anyobs[t] = OR over b
__global__ void prep_obs(const float* __restrict__ ca, const float* __restrict__ cb,
                         const float* __restrict__ cc2, const float* __restrict__ cd,
                         const float4* __restrict__ si, int* __restrict__ anyobs,
                         unsigned char* __restrict__ obs) {
  int grp = blockIdx.x * (blockDim.x >> 5) + (threadIdx.x >> 5);
  int lane = threadIdx.x & 31;
  int t = grp & (TT - 1);
  int b = grp / TT;
  int ch = 1 + lane;
  float4 s = si[t];
  int idx = __float_as_int(s.x);
  float fr = s.y;
  size_t base = ((size_t)b * (TT - 1) + idx) * CC + ch;
  float f3 = fr / 3.f;
  float v = ca[base] + (cb[base] + (0.5f * cc2[base] + cd[base] * f3) * fr) * fr;
  float D = v;
  if (t >= 1) {
    float4 sp = si[t - 1];
    int idxp = __float_as_int(sp.x);
    float frp = sp.y;
    size_t basep = ((size_t)b * (TT - 1) + idxp) * CC + ch;
    float f3p = frp / 3.f;
    float vp = ca[basep] + (cb[basep] + (0.5f * cc2[basep] + cd[basep] * f3p) * frp) * frp;
    D = v - vp;
  }
  float m = D;
  #pragma unroll
  for (int off = 16; off >= 1; off >>= 1) m = fmaxf(m, __shfl_xor(m, off));
  if (lane == 0) {
    unsigned char o = (m > 0.5f) ? (unsigned char)1 : (unsigned char)0;
    obs[(size_t)b * TT + t] = o;
    if (o) atomicOr(&anyobs[t], 1);
  }
}

// One block per batch element. 512 threads. Thread (wv, jslot=lane>>4, kk=lane&15)
// owns outputs jbase..jbase+3 (jbase = wv*16+jslot*4) over k-rows 8kk..8kk+7.
// Reduction over kk via DPP row_ror (VALU). LDS traffic: 2 b128 reads + 1 b128
// write (kk==0) per wave per stage.
__launch_bounds__(512, 2)
__global__ void ode_main(
    const float* __restrict__ ca, const float* __restrict__ cb,
    const float* __restrict__ cc2, const float* __restrict__ cd,
    const int* __restrict__ final_index,
    const float* __restrict__ Wr, const float* __restrict__ br,
    const float* __restrict__ Wz, const float* __restrict__ bz,
    const float* __restrict__ Wxn, const float* __restrict__ bxn,
    const float* __restrict__ Whn, const float* __restrict__ bhn,
    const float* __restrict__ Wode, const float* __restrict__ bode,
    const float* __restrict__ Wlin, const float* __restrict__ blin,
    const float4* __restrict__ si, const int* __restrict__ anyobs,
    const unsigned char* __restrict__ obsArr,
    float* __restrict__ out)
{
  __shared__ alignas(16) float hS[HID];
  __shared__ alignas(16) float vA[HID];
  __shared__ alignas(16) float vB[HID];
  __shared__ alignas(16) float xs[HALFC];

  const int tid = threadIdx.x;
  const int b = blockIdx.x;
  const int lane = tid & 63;
  const int wv = tid >> 6;
  const int jslot = lane >> 4;
  const int kk = lane & 15;
  const int jbase = wv * 16 + jslot * 4;
  const int myslot = swz(wv * 4 + jslot);

  // ---- weights in registers: [r][m] with row = 8*kk + r (h-parts) ----
  float wode[32], whn[32], wrh[32], wzh[32];
  float wrx[8], wzx[8], wxn[8];
  #pragma unroll
  for (int r = 0; r < 8; ++r) {
    const int row = 8 * kk + r;
    float4 q;
    q = *(const float4*)&Wode[row * HID + jbase];
    wode[r*4+0]=q.x; wode[r*4+1]=q.y; wode[r*4+2]=q.z; wode[r*4+3]=q.w;
    q = *(const float4*)&Whn[row * HID + jbase];
    whn[r*4+0]=q.x; whn[r*4+1]=q.y; whn[r*4+2]=q.z; whn[r*4+3]=q.w;
    q = *(const float4*)&Wr[(HALFC + row) * HID + jbase];
    wrh[r*4+0]=q.x; wrh[r*4+1]=q.y; wrh[r*4+2]=q.z; wrh[r*4+3]=q.w;
    q = *(const float4*)&Wz[(HALFC + row) * HID + jbase];
    wzh[r*4+0]=q.x; wzh[r*4+1]=q.y; wzh[r*4+2]=q.z; wzh[r*4+3]=q.w;
  }
  #pragma unroll
  for (int r2 = 0; r2 < 2; ++r2) {
    const int xrow = 2 * kk + r2;
    float4 q;
    q = *(const float4*)&Wr[xrow * HID + jbase];
    wrx[r2*4+0]=q.x; wrx[r2*4+1]=q.y; wrx[r2*4+2]=q.z; wrx[r2*4+3]=q.w;
    q = *(const float4*)&Wz[xrow * HID + jbase];
    wzx[r2*4+0]=q.x; wzx[r2*4+1]=q.y; wzx[r2*4+2]=q.z; wzx[r2*4+3]=q.w;
    q = *(const float4*)&Wxn[xrow * HID + jbase];
    wxn[r2*4+0]=q.x; wxn[r2*4+1]=q.y; wxn[r2*4+2]=q.z; wxn[r2*4+3]=q.w;
  }
  float bo[4], bh[4], brj[4], bzj[4], bxj[4];
  {
    float4 q;
    q = *(const float4*)&bode[jbase]; bo[0]=q.x; bo[1]=q.y; bo[2]=q.z; bo[3]=q.w;
    q = *(const float4*)&bhn[jbase];  bh[0]=q.x; bh[1]=q.y; bh[2]=q.z; bh[3]=q.w;
    q = *(const float4*)&br[jbase];   brj[0]=q.x; brj[1]=q.y; brj[2]=q.z; brj[3]=q.w;
    q = *(const float4*)&bz[jbase];   bzj[0]=q.x; bzj[1]=q.y; bzj[2]=q.z; bzj[3]=q.w;
    q = *(const float4*)&bxn[jbase];  bxj[0]=q.x; bxj[1]=q.y; bxj[2]=q.z; bxj[3]=q.w;
  }
  const int fidx = final_index[b];

  if (tid < HID) { hS[tid] = 0.f; vA[tid] = 0.f; vB[tid] = 0.f; }
  if (tid < HALFC) xs[tid] = 0.f;
  float hj[4] = {0.f, 0.f, 0.f, 0.f};
  float dtv = 0.f;  // meaningful on tid 0
  __syncthreads();

  // W_ode matvec stage: v(LDS) -> k[4] = tanh(reduced + bias)
  auto mv_ode = [&](const float* __restrict__ vsrc, float kout[4]) {
    const float4* v4 = (const float4*)vsrc;
    const float4 A = v4[swz(2 * kk)];
    const float4 B4 = v4[swz(2 * kk + 1)];
    const float vv[8] = {A.x, A.y, A.z, A.w, B4.x, B4.y, B4.z, B4.w};
    float acc[4] = {0.f, 0.f, 0.f, 0.f};
    #pragma unroll
    for (int r = 0; r < 8; ++r)
      #pragma unroll
      for (int m = 0; m < 4; ++m)
        acc[m] = fmaf(vv[r], wode[r * 4 + m], acc[m]);
    #pragma unroll
    for (int m = 0; m < 4; ++m) kout[m] = ftanh(red16(acc[m]) + bo[m]);
  };

  float4 s = si[0];
  int aob = anyobs[0];
  int ob = (int)obsArr[(size_t)b * TT];

  for (int t = 0; ; ++t) {
    const int sidx = __float_as_int(s.x);
    const float fr = s.y, td = s.z, tsub = s.w;
    const bool apply = (aob != 0) && (ob != 0);
    float xdelta = 0.f;

    // Issue x-coeff loads early (tid<32); consumed after RK4.
    float xa = 0.f, xb = 0.f, xc = 0.f, xd = 0.f;
    float ya = 0.f, yb = 0.f, yc = 0.f, yd = 0.f;
    if (tid < 32) {
      const size_t base = ((size_t)b * (TT - 1) + sidx) * CC;
      const int ch = 33 + tid;
      xa = ca[base + ch]; xb = cb[base + ch]; xc = cc2[base + ch]; xd = cd[base + ch];
      if (tid == 0) { ya = ca[base]; yb = cb[base]; yc = cc2[base]; yd = cd[base]; }
    }
    // Prefetch next step's scalars (hides L2 latency behind this step's body)
    const int tn = (t < TT - 1) ? t + 1 : t;
    const float4 sN = si[tn];
    const int aobN = anyobs[tn];
    const int obN = (int)obsArr[(size_t)b * TT + tn];

    if (t > 0) {
      const float htd = 0.5f * td;
      float k[4], ks[4];
      mv_ode(hS, k);
      #pragma unroll
      for (int m = 0; m < 4; ++m) ks[m] = k[m];
      if (kk == 0)
        ((float4*)vA)[myslot] = make_float4(
            fmaf(htd, k[0], hj[0]), fmaf(htd, k[1], hj[1]),
            fmaf(htd, k[2], hj[2]), fmaf(htd, k[3], hj[3]));
      __syncthreads();
      mv_ode(vA, k);
      #pragma unroll
      for (int m = 0; m < 4; ++m) ks[m] = fmaf(2.f, k[m], ks[m]);
      if (kk == 0)
        ((float4*)vB)[myslot] = make_float4(
            fmaf(htd, k[0], hj[0]), fmaf(htd, k[1], hj[1]),
            fmaf(htd, k[2], hj[2]), fmaf(htd, k[3], hj[3]));
      __syncthreads();
      mv_ode(vB, k);
      #pragma unroll
      for (int m = 0; m < 4; ++m) ks[m] = fmaf(2.f, k[m], ks[m]);
      if (kk == 0)
        ((float4*)vA)[myslot] = make_float4(
            fmaf(td, k[0], hj[0]), fmaf(td, k[1], hj[1]),
            fmaf(td, k[2], hj[2]), fmaf(td, k[3], hj[3]));
      __syncthreads();
      mv_ode(vA, k);
      #pragma unroll
      for (int m = 0; m < 4; ++m) {
        ks[m] += k[m];
        hj[m] = fmaf(td * (1.f / 6.f), ks[m], hj[m]);
      }
      if (kk == 0)
        ((float4*)vB)[myslot] = make_float4(hj[0], hj[1], hj[2], hj[3]);
    }

    // Spline -> xs (tid<32). vB holds h_evolved (zeros at t=0).
    if (tid < 32) {
      const float f3 = fr * (1.f / 3.f);
      float sv = xa + (xb + (0.5f * xc + xd * f3) * fr) * fr;
      if (tid == 0) {
        const float s0 = ya + (yb + (0.5f * yc + yd * f3) * fr) * fr;
        xdelta = s0 - tsub;
        sv += dtv;  // Xp[:,0] += dt
      }
      xs[tid] = sv;
    }
    __syncthreads();

    // GRU
    {
      const float4* v4 = (const float4*)vB;
      const float4 A = v4[swz(2 * kk)];
      const float4 B4 = v4[swz(2 * kk + 1)];
      const float vv[8] = {A.x, A.y, A.z, A.w, B4.x, B4.y, B4.z, B4.w};
      float rp[4] = {0.f,0.f,0.f,0.f}, zp[4] = {0.f,0.f,0.f,0.f};
      float hp[4] = {0.f,0.f,0.f,0.f}, xp[4] = {0.f,0.f,0.f,0.f};
      #pragma unroll
      for (int r = 0; r < 8; ++r)
        #pragma unroll
        for (int m = 0; m < 4; ++m) {
          rp[m] = fmaf(vv[r], wrh[r * 4 + m], rp[m]);
          zp[m] = fmaf(vv[r], wzh[r * 4 + m], zp[m]);
          hp[m] = fmaf(vv[r], whn[r * 4 + m], hp[m]);
        }
      const float2 xv = ((const float2*)xs)[kk];
      #pragma unroll
      for (int m = 0; m < 4; ++m) {
        rp[m] = fmaf(xv.x, wrx[m], fmaf(xv.y, wrx[4 + m], rp[m]));
        zp[m] = fmaf(xv.x, wzx[m], fmaf(xv.y, wzx[4 + m], zp[m]));
        xp[m] = fmaf(xv.x, wxn[m], fmaf(xv.y, wxn[4 + m], xp[m]));
      }
      #pragma unroll
      for (int m = 0; m < 4; ++m) {
        rp[m] = red16(rp[m]); zp[m] = red16(zp[m]);
        hp[m] = red16(hp[m]); xp[m] = red16(xp[m]);
      }
      #pragma unroll
      for (int m = 0; m < 4; ++m) {
        const float r = fsig(rp[m] + brj[m]);
        const float z = fsig(zp[m] + bzj[m]);
        const float n = ftanh(xp[m] + bxj[m] + (hp[m] + bh[m]) * r);
        const float hnew = fmaf(z, hj[m] - n, n);  // (1-z)*n + z*h
        hj[m] = apply ? hnew : hj[m];
      }
      if (kk == 0)
        ((float4*)hS)[myslot] = make_float4(hj[0], hj[1], hj[2], hj[3]);
    }
    if (tid == 0 && aob && !ob) dtv += xdelta;
    __syncthreads();
    if (t == fidx) break;
    s = sN; aob = aobN; ob = obN;
  }

  // final projection: out = h @ W_lin + b_lin  (de-swizzle hS reads)
  if (tid < ODIM) {
    float acc = blin[tid];
    #pragma unroll 8
    for (int q = 0; q < HID; ++q) {
      const float hv = hS[swz(q >> 2) * 4 + (q & 3)];
      acc = fmaf(hv, Wlin[q * ODIM + tid], acc);
    }
    out[b * ODIM + tid] = acc;
  }
}

extern "C" void kernel_launch(void* const* d_in, const int* in_sizes, int n_in,
                              void* d_out, int out_size, void* d_ws, size_t ws_size,
                              hipStream_t stream) {
  const float* times = (const float*)d_in[0];
  const float* ca   = (const float*)d_in[1];
  const float* cb   = (const float*)d_in[2];
  const float* cc2  = (const float*)d_in[3];
  const float* cd   = (const float*)d_in[4];
  const int*   fidx = (const int*)d_in[5];
  const float* Wr   = (const float*)d_in[6];
  const float* br   = (const float*)d_in[7];
  const float* Wz   = (const float*)d_in[8];
  const float* bz   = (const float*)d_in[9];
  const float* Wxn  = (const float*)d_in[10];
  const float* bxn  = (const float*)d_in[11];
  const float* Whn  = (const float*)d_in[12];
  const float* bhn  = (const float*)d_in[13];
  const float* Wode = (const float*)d_in[14];
  const float* bode = (const float*)d_in[15];
  const float* Wlin = (const float*)d_in[16];
  const float* blin = (const float*)d_in[17];
  float* out = (float*)d_out;

  char* ws = (char*)d_ws;
  float4* si = (float4*)ws;                                     // TT*16 B
  int* anyobs = (int*)(ws + TT * 16);                           // TT*4 B
  unsigned char* obs = (unsigned char*)(ws + TT * 16 + TT * 4); // BB*TT B

  prep0<<<1, TT, 0, stream>>>(times, si, anyobs);
  prep_obs<<<(BB * TT) / 8, 256, 0, stream>>>(ca, cb, cc2, cd, si, anyobs, obs);
  ode_main<<<BB, 512, 0, stream>>>(ca, cb, cc2, cd, fidx, Wr, br, Wz, bz,
                                   Wxn, bxn, Whn, bhn, Wode, bode, Wlin, blin,
                                   si, anyobs, obs, out);
}

// Round 5
// 1100.620 us; speedup vs baseline: 1.8319x; 1.8319x over previous
//
#include <hip/hip_runtime.h>

#define TT 512
#define BB 256
#define CC 65
#define HALFC 32
#define HID 128
#define ODIM 10

// tanh(x) = 2/(1+e^{-2x}) - 1 : mul, exp2, add, rcp, fma (2 transcendentals)
__device__ __forceinline__ float ftanh(float x) {
  float u = __builtin_amdgcn_exp2f(x * -2.885390082f);  // e^{-2x}
  return fmaf(2.f, __builtin_amdgcn_rcpf(1.f + u), -1.f);
}
// sigmoid(x) = 1/(1+e^{-x})
__device__ __forceinline__ float fsig(float x) {
  float u = __builtin_amdgcn_exp2f(x * -1.442695041f);
  return __builtin_amdgcn_rcpf(1.f + u);
}

template <int CTRL>
__device__ __forceinline__ float dpp_add(float x) {
  return x + __int_as_float(__builtin_amdgcn_update_dpp(
      0, __float_as_int(x), CTRL, 0xF, 0xF, true));
}
// 8-lane subgroup sum via row_shl (data moves toward LOWER lanes; bound_ctrl
// zeros beyond the row edge): dest[i] = sum src[i..i+7]. Valid at (lane&7)==0
// (lanes 0 and 8 of each DPP 16-row are clean — no cross-subgroup pollution).
__device__ __forceinline__ float red8(float x) {
  x = dpp_add<0x101>(x);  // row_shl:1
  x = dpp_add<0x102>(x);  // row_shl:2
  x = dpp_add<0x104>(x);  // row_shl:4
  return x;
}

// Raw barrier: drain LDS ops, no vmcnt drain (global loads stay in flight).
__device__ __forceinline__ void block_sync_lds() {
  asm volatile("s_waitcnt lgkmcnt(0)" ::: "memory");
  __builtin_amdgcn_s_barrier();
  asm volatile("" ::: "memory");
}
__device__ __forceinline__ void vm_wait0() {
  asm volatile("s_waitcnt vmcnt(0)" ::: "memory");
}

// Permuted 128-float LDS layout: logical float4 f (=v[4f..4f+3]) stored at
// float4 index perm(f) = ((f&3)<<3) | (f>>2). Thread kk's k-slice
// {v[16kk+4q+e]} is logical f=4kk+q -> stored q*8+kk: each read instruction
// (fixed q, kk=0..7) touches 8 consecutive float4s = all 32 banks once.
__device__ __forceinline__ int permf4(int f) { return ((f & 3) << 3) | (f >> 2); }
// Writer: output-pair slot s (floats 2s,2s+1) -> byte offset in buffer.
__device__ __forceinline__ int slot_byteoff(int s) {
  return permf4(s >> 1) * 16 + (s & 1) * 8;
}

// Per-t scalars: idx (int bits), fr, td, tsub
__global__ void prep0(const float* __restrict__ times, float4* __restrict__ si,
                      int* __restrict__ anyobs) {
  __shared__ float ts[TT];
  int t = threadIdx.x;
  ts[t] = times[t];
  __syncthreads();
  float tv = ts[t];
  int cnt = 0;
  for (int jj = 0; jj < TT; ++jj) cnt += (tv > ts[jj]) ? 1 : 0;
  int idx = cnt - 1;
  idx = min(max(idx, 0), TT - 2);
  float4 o;
  o.x = __int_as_float(idx);
  o.y = tv - ts[idx];
  o.z = (t == 0) ? 0.f : (tv - ts[t - 1]);
  o.w = (t == 0) ? ts[0] : ts[t - 1];
  si[t] = o;
  anyobs[t] = 0;
}

// obs[b,t] = max over diffed channels 1..32 > 0.5 ; anyobs[t] = OR over b
__global__ void prep_obs(const float* __restrict__ ca, const float* __restrict__ cb,
                         const float* __restrict__ cc2, const float* __restrict__ cd,
                         const float4* __restrict__ si, int* __restrict__ anyobs,
                         unsigned char* __restrict__ obs) {
  int grp = blockIdx.x * (blockDim.x >> 5) + (threadIdx.x >> 5);
  int lane = threadIdx.x & 31;
  int t = grp & (TT - 1);
  int b = grp / TT;
  int ch = 1 + lane;
  float4 s = si[t];
  int idx = __float_as_int(s.x);
  float fr = s.y;
  size_t base = ((size_t)b * (TT - 1) + idx) * CC + ch;
  float f3 = fr / 3.f;
  float v = ca[base] + (cb[base] + (0.5f * cc2[base] + cd[base] * f3) * fr) * fr;
  float D = v;
  if (t >= 1) {
    float4 sp = si[t - 1];
    int idxp = __float_as_int(sp.x);
    float frp = sp.y;
    size_t basep = ((size_t)b * (TT - 1) + idxp) * CC + ch;
    float f3p = frp / 3.f;
    float vp = ca[basep] + (cb[basep] + (0.5f * cc2[basep] + cd[basep] * f3p) * frp) * frp;
    D = v - vp;
  }
  float m = D;
  #pragma unroll
  for (int off = 16; off >= 1; off >>= 1) m = fmaxf(m, __shfl_xor(m, off));
  if (lane == 0) {
    unsigned char o = (m > 0.5f) ? (unsigned char)1 : (unsigned char)0;
    obs[(size_t)b * TT + t] = o;
    if (o) atomicOr(&anyobs[t], 1);
  }
}

// One block per batch element. 512 threads. Thread (wv, jslot=lane>>3, kk=lane&7)
// owns output pair j0 = wv*16 + jslot*2 over k-rows 16kk..16kk+15.
// Reduction over kk: 3 DPP row_shl adds (valid at kk==0, which also writes).
__launch_bounds__(512, 2)
__global__ void ode_main(
    const float* __restrict__ ca, const float* __restrict__ cb,
    const float* __restrict__ cc2, const float* __restrict__ cd,
    const int* __restrict__ final_index,
    const float* __restrict__ Wr, const float* __restrict__ br,
    const float* __restrict__ Wz, const float* __restrict__ bz,
    const float* __restrict__ Wxn, const float* __restrict__ bxn,
    const float* __restrict__ Whn, const float* __restrict__ bhn,
    const float* __restrict__ Wode, const float* __restrict__ bode,
    const float* __restrict__ Wlin, const float* __restrict__ blin,
    const float4* __restrict__ si, const int* __restrict__ anyobs,
    const unsigned char* __restrict__ obsArr,
    float* __restrict__ out)
{
  __shared__ alignas(16) float hS[HID];
  __shared__ alignas(16) float vA[HID];
  __shared__ alignas(16) float vB[HID];
  __shared__ alignas(16) float xs[HALFC];
  __shared__ alignas(16) float4 siL[TT];
  __shared__ unsigned char flagL[TT];

  const int tid = threadIdx.x;
  const int b = blockIdx.x;
  const int lane = tid & 63;
  const int wv = tid >> 6;
  const int jslot = lane >> 3;   // 0..7
  const int kk = lane & 7;       // 0..7
  const int j0 = wv * 16 + jslot * 2;
  const int wroff = slot_byteoff(wv * 8 + jslot);

  // ---- weights in registers: w[2*i+m] = W[(16*kk+i)*HID + j0+m] ----
  float wode[32], whn[32], wrh[32], wzh[32];
  float wrx[8], wzx[8], wxn[8];
  #pragma unroll
  for (int i = 0; i < 16; ++i) {
    const int row = 16 * kk + i;
    float2 q;
    q = *(const float2*)&Wode[row * HID + j0]; wode[2*i] = q.x; wode[2*i+1] = q.y;
    q = *(const float2*)&Whn [row * HID + j0]; whn [2*i] = q.x; whn [2*i+1] = q.y;
    q = *(const float2*)&Wr[(HALFC + row) * HID + j0]; wrh[2*i] = q.x; wrh[2*i+1] = q.y;
    q = *(const float2*)&Wz[(HALFC + row) * HID + j0]; wzh[2*i] = q.x; wzh[2*i+1] = q.y;
  }
  #pragma unroll
  for (int i = 0; i < 4; ++i) {
    const int xrow = 4 * kk + i;
    float2 q;
    q = *(const float2*)&Wr [xrow * HID + j0]; wrx[2*i] = q.x; wrx[2*i+1] = q.y;
    q = *(const float2*)&Wz [xrow * HID + j0]; wzx[2*i] = q.x; wzx[2*i+1] = q.y;
    q = *(const float2*)&Wxn[xrow * HID + j0]; wxn[2*i] = q.x; wxn[2*i+1] = q.y;
  }
  float bo0, bo1, bh0, bh1, br0, br1, bz0, bz1, bx0, bx1;
  { float2 q;
    q = *(const float2*)&bode[j0]; bo0 = q.x; bo1 = q.y;
    q = *(const float2*)&bhn [j0]; bh0 = q.x; bh1 = q.y;
    q = *(const float2*)&br  [j0]; br0 = q.x; br1 = q.y;
    q = *(const float2*)&bz  [j0]; bz0 = q.x; bz1 = q.y;
    q = *(const float2*)&bxn [j0]; bx0 = q.x; bx1 = q.y;
  }
  const int fidx = final_index[b];

  // ---- stage per-step metadata into LDS (one-time) ----
  {
    siL[tid] = si[tid];
    const int ao = anyobs[tid];
    const unsigned char o = obsArr[(size_t)b * TT + tid];
    flagL[tid] = (unsigned char)((ao ? 1 : 0) | (o ? 2 : 0));
  }
  if (tid < HID) { hS[tid] = 0.f; vA[tid] = 0.f; vB[tid] = 0.f; }
  if (tid < HALFC) xs[tid] = 0.f;
  float hj0 = 0.f, hj1 = 0.f;  // valid on kk==0 lanes
  float dtv = 0.f;             // valid on tid==0
  block_sync_lds();

  // matvec over permuted LDS buffer: per-thread 16 k-rows x 2 outputs.
  auto mv = [&](const float* __restrict__ buf, const float (&w)[32],
                float& o0, float& o1) {
    const float4* b4 = (const float4*)buf;
    float vv[16];
    #pragma unroll
    for (int q = 0; q < 4; ++q) {
      const float4 x4 = b4[q * 8 + kk];
      vv[4*q] = x4.x; vv[4*q+1] = x4.y; vv[4*q+2] = x4.z; vv[4*q+3] = x4.w;
    }
    float a0 = 0.f, a1 = 0.f;
    #pragma unroll
    for (int i = 0; i < 16; ++i) {
      a0 = fmaf(vv[i], w[2*i],   a0);
      a1 = fmaf(vv[i], w[2*i+1], a1);
    }
    o0 = red8(a0); o1 = red8(a1);
  };

  float4 s = siL[0];
  int flg = flagL[0];

  for (int t = 0; ; ++t) {
    const int sidx = __float_as_int(s.x);
    const float fr = s.y, td = s.z, tsub = s.w;
    const bool apply = (flg & 1) && (flg & 2);

    // Issue x-coeff global loads early; they stay in flight across the raw
    // barriers (no vmcnt drain) and are waited just before the spline.
    float xa = 0.f, xb = 0.f, xc = 0.f, xd = 0.f;
    float ya = 0.f, yb = 0.f, yc = 0.f, yd = 0.f;
    if (tid < 32) {
      const size_t base = ((size_t)b * (TT - 1) + sidx) * CC;
      const int ch = 33 + tid;
      xa = ca[base + ch]; xb = cb[base + ch]; xc = cc2[base + ch]; xd = cd[base + ch];
      if (tid == 0) { ya = ca[base]; yb = cb[base]; yc = cc2[base]; yd = cd[base]; }
    }

    if (t > 0) {
      const float htd = 0.5f * td;
      float p0, p1, k0, k1, ks0, ks1;
      // stage 1: k1 = f(h)
      mv(hS, wode, p0, p1);
      k0 = ftanh(p0 + bo0); k1 = ftanh(p1 + bo1);
      ks0 = k0; ks1 = k1;
      if (kk == 0)
        *(float2*)((char*)vA + wroff) =
            make_float2(fmaf(htd, k0, hj0), fmaf(htd, k1, hj1));
      block_sync_lds();
      // stage 2: k2 = f(h + td/2 k1)
      mv(vA, wode, p0, p1);
      k0 = ftanh(p0 + bo0); k1 = ftanh(p1 + bo1);
      ks0 = fmaf(2.f, k0, ks0); ks1 = fmaf(2.f, k1, ks1);
      if (kk == 0)
        *(float2*)((char*)vB + wroff) =
            make_float2(fmaf(htd, k0, hj0), fmaf(htd, k1, hj1));
      block_sync_lds();
      // stage 3: k3 = f(h + td/2 k2)
      mv(vB, wode, p0, p1);
      k0 = ftanh(p0 + bo0); k1 = ftanh(p1 + bo1);
      ks0 = fmaf(2.f, k0, ks0); ks1 = fmaf(2.f, k1, ks1);
      if (kk == 0)
        *(float2*)((char*)vA + wroff) =
            make_float2(fmaf(td, k0, hj0), fmaf(td, k1, hj1));
      block_sync_lds();
      // stage 4: k4 = f(h + td k3); h += td/6 (k1+2k2+2k3+k4)
      mv(vA, wode, p0, p1);
      k0 = ftanh(p0 + bo0); k1 = ftanh(p1 + bo1);
      ks0 += k0; ks1 += k1;
      hj0 = fmaf(td * (1.f / 6.f), ks0, hj0);
      hj1 = fmaf(td * (1.f / 6.f), ks1, hj1);
      if (kk == 0)
        *(float2*)((char*)vB + wroff) = make_float2(hj0, hj1);
    }

    // Spline -> xs (tid<32). Wait for the global loads here (hidden under RK4).
    float xdelta = 0.f;
    vm_wait0();
    if (tid < 32) {
      const float f3 = fr * (1.f / 3.f);
      float sv = xa + (xb + (0.5f * xc + xd * f3) * fr) * fr;
      if (tid == 0) {
        const float s0 = ya + (yb + (0.5f * yc + yd * f3) * fr) * fr;
        xdelta = s0 - tsub;
        sv += dtv;  // Xp[:,0] += dt
      }
      xs[tid] = sv;
    }
    block_sync_lds();  // covers vB (evolved h) and xs

    // GRU
    {
      const float4* b4 = (const float4*)vB;
      float vv[16];
      #pragma unroll
      for (int q = 0; q < 4; ++q) {
        const float4 x4 = b4[q * 8 + kk];
        vv[4*q] = x4.x; vv[4*q+1] = x4.y; vv[4*q+2] = x4.z; vv[4*q+3] = x4.w;
      }
      float rp0 = 0.f, rp1 = 0.f, zp0 = 0.f, zp1 = 0.f;
      float gp0 = 0.f, gp1 = 0.f, xp0 = 0.f, xp1 = 0.f;
      #pragma unroll
      for (int i = 0; i < 16; ++i) {
        rp0 = fmaf(vv[i], wrh[2*i],   rp0); rp1 = fmaf(vv[i], wrh[2*i+1], rp1);
        zp0 = fmaf(vv[i], wzh[2*i],   zp0); zp1 = fmaf(vv[i], wzh[2*i+1], zp1);
        gp0 = fmaf(vv[i], whn[2*i],   gp0); gp1 = fmaf(vv[i], whn[2*i+1], gp1);
      }
      const float4 xq = ((const float4*)xs)[kk];
      const float xv[4] = {xq.x, xq.y, xq.z, xq.w};
      #pragma unroll
      for (int i = 0; i < 4; ++i) {
        rp0 = fmaf(xv[i], wrx[2*i],   rp0); rp1 = fmaf(xv[i], wrx[2*i+1], rp1);
        zp0 = fmaf(xv[i], wzx[2*i],   zp0); zp1 = fmaf(xv[i], wzx[2*i+1], zp1);
        xp0 = fmaf(xv[i], wxn[2*i],   xp0); xp1 = fmaf(xv[i], wxn[2*i+1], xp1);
      }
      rp0 = red8(rp0); rp1 = red8(rp1);
      zp0 = red8(zp0); zp1 = red8(zp1);
      gp0 = red8(gp0); gp1 = red8(gp1);
      xp0 = red8(xp0); xp1 = red8(xp1);
      // acts computed on all lanes; only kk==0's values are valid/stored
      const float r0 = fsig(rp0 + br0), r1 = fsig(rp1 + br1);
      const float z0 = fsig(zp0 + bz0), z1 = fsig(zp1 + bz1);
      const float n0 = ftanh(xp0 + bx0 + (gp0 + bh0) * r0);
      const float n1 = ftanh(xp1 + bx1 + (gp1 + bh1) * r1);
      const float h0n = fmaf(z0, hj0 - n0, n0);
      const float h1n = fmaf(z1, hj1 - n1, n1);
      hj0 = apply ? h0n : hj0;
      hj1 = apply ? h1n : hj1;
      if (kk == 0)
        *(float2*)((char*)hS + wroff) = make_float2(hj0, hj1);
    }
    if (tid == 0 && (flg & 1) && !(flg & 2)) dtv += xdelta;

    if (t == fidx) break;
    // prefetch next step's metadata from LDS
    const int tn = t + 1;
    s = siL[tn];
    flg = flagL[tn];
    block_sync_lds();  // hS visible for next stage 1
  }

  block_sync_lds();
  // final projection: out = h @ W_lin + b_lin (de-permute hS reads)
  if (tid < ODIM) {
    float acc = blin[tid];
    const float* hf = (const float*)hS;
    #pragma unroll 8
    for (int q = 0; q < HID; ++q) {
      const float hv = hf[permf4(q >> 2) * 4 + (q & 3)];
      acc = fmaf(hv, Wlin[q * ODIM + tid], acc);
    }
    out[b * ODIM + tid] = acc;
  }
}

extern "C" void kernel_launch(void* const* d_in, const int* in_sizes, int n_in,
                              void* d_out, int out_size, void* d_ws, size_t ws_size,
                              hipStream_t stream) {
  const float* times = (const float*)d_in[0];
  const float* ca   = (const float*)d_in[1];
  const float* cb   = (const float*)d_in[2];
  const float* cc2  = (const float*)d_in[3];
  const float* cd   = (const float*)d_in[4];
  const int*   fidx = (const int*)d_in[5];
  const float* Wr   = (const float*)d_in[6];
  const float* br   = (const float*)d_in[7];
  const float* Wz   = (const float*)d_in[8];
  const float* bz   = (const float*)d_in[9];
  const float* Wxn  = (const float*)d_in[10];
  const float* bxn  = (const float*)d_in[11];
  const float* Whn  = (const float*)d_in[12];
  const float* bhn  = (const float*)d_in[13];
  const float* Wode = (const float*)d_in[14];
  const float* bode = (const float*)d_in[15];
  const float* Wlin = (const float*)d_in[16];
  const float* blin = (const float*)d_in[17];
  float* out = (float*)d_out;

  char* ws = (char*)d_ws;
  float4* si = (float4*)ws;                                     // TT*16 B
  int* anyobs = (int*)(ws + TT * 16);                           // TT*4 B
  unsigned char* obs = (unsigned char*)(ws + TT * 16 + TT * 4); // BB*TT B

  prep0<<<1, TT, 0, stream>>>(times, si, anyobs);
  prep_obs<<<(BB * TT) / 8, 256, 0, stream>>>(ca, cb, cc2, cd, si, anyobs, obs);
  ode_main<<<BB, 512, 0, stream>>>(ca, cb, cc2, cd, fidx, Wr, br, Wz, bz,
                                   Wxn, bxn, Whn, bhn, Wode, bode, Wlin, blin,
                                   si, anyobs, obs, out);
}